// Round 1
// baseline (3557.213 us; speedup 1.0000x reference)
//
#include <hip/hip_runtime.h>
#include <math.h>

#define NN 20000
#define NF 32
#define BM 256                       // rows per workgroup
#define BK 32                        // k-tile
#define NSEG 25                      // k-split segments
#define SEGLEN (NN / NSEG)           // 800
#define NTILES (SEGLEN / BK)         // 25
#define ROWBLK ((NN + BM - 1) / BM)  // 79
#define LDS_STRIDE 33                // +1 pad: transposed-read banks (l+kk)%32 -> 2-way (free)
#define BN_EPS 1e-5f

// ---------------- zero workspace (h1 accumulator + stats) ----------------
__global__ __launch_bounds__(256) void zero_ws(float* ws) {
    const int total = NN * NF + 2 * NF;
    for (int i = blockIdx.x * 256 + threadIdx.x; i < total; i += gridDim.x * 256)
        ws[i] = 0.0f;
}

// ---------------- h1 += A[rows, kseg] @ X[kseg, :] ----------------
__global__ __launch_bounds__(256, 4)
void aggregate_kernel(const float* __restrict__ A, const float* __restrict__ X,
                      float* __restrict__ h1) {
    __shared__ float lds[BM * LDS_STRIDE];
    const int tid  = threadIdx.x;
    const int rb   = blockIdx.x % ROWBLK;
    const int seg  = blockIdx.x / ROWBLK;
    const int row0 = rb * BM;
    const int kbase = seg * SEGLEN;

    float acc[NF];
#pragma unroll
    for (int c = 0; c < NF; ++c) acc[c] = 0.0f;

    const int q    = tid & 7;   // float4 column within 32-wide k-tile
    const int rsub = tid >> 3;  // 0..31

    for (int kt = 0; kt < NTILES; ++kt) {
        const int k0 = kbase + kt * BK;
        __syncthreads();  // previous tile's reads done before overwrite
        // stage A[row0..row0+255][k0..k0+31] -> LDS (coalesced 128B runs per row)
#pragma unroll
        for (int j = 0; j < 8; ++j) {
            const int r = rsub + j * 32;
            const int grow = row0 + r;
            float4 v = make_float4(0.f, 0.f, 0.f, 0.f);
            if (grow < NN)
                v = *(const float4*)(A + (size_t)grow * NN + k0 + q * 4);
            float* d = &lds[r * LDS_STRIDE + q * 4];
            d[0] = v.x; d[1] = v.y; d[2] = v.z; d[3] = v.w;
        }
        __syncthreads();

        const float* __restrict__ xk = X + (size_t)k0 * NF;  // wave-uniform -> s_load
#pragma unroll 8
        for (int kk = 0; kk < BK; ++kk) {
            const float a = lds[tid * LDS_STRIDE + kk];   // 2-way bank alias: free
            const float* __restrict__ xrow = xk + kk * NF;
#pragma unroll
            for (int c = 0; c < NF; ++c)
                acc[c] = fmaf(a, xrow[c], acc[c]);        // v_fmac_f32 vdst, sX, vA
        }
    }

    const int grow = row0 + tid;
    if (grow < NN) {
#pragma unroll
        for (int c = 0; c < NF; ++c)
            unsafeAtomicAdd(&h1[(size_t)grow * NF + c], acc[c]);
    }
}

// ---------------- y = h1 @ W (in-place) + column sum/sumsq ----------------
__global__ __launch_bounds__(256)
void transform_kernel(float* __restrict__ h1, const float* __restrict__ W,
                      float* __restrict__ stats) {
    const int row = blockIdx.x * 256 + threadIdx.x;
    const bool valid = row < NN;

    float h[NF];
    if (valid) {
        const float4* hp = (const float4*)(h1 + (size_t)row * NF);
#pragma unroll
        for (int v = 0; v < NF / 4; ++v) {
            float4 t = hp[v];
            h[v * 4 + 0] = t.x; h[v * 4 + 1] = t.y; h[v * 4 + 2] = t.z; h[v * 4 + 3] = t.w;
        }
    } else {
#pragma unroll
        for (int c = 0; c < NF; ++c) h[c] = 0.0f;
    }

    float y[NF];
#pragma unroll
    for (int c = 0; c < NF; ++c) {
        float s = 0.0f;
#pragma unroll
        for (int i = 0; i < NF; ++i)
            s = fmaf(h[i], W[i * NF + c], s);  // W uniform -> s_load
        y[c] = s;
    }

    if (valid) {
        float4* hp = (float4*)(h1 + (size_t)row * NF);
#pragma unroll
        for (int v = 0; v < NF / 4; ++v)
            hp[v] = make_float4(y[v * 4], y[v * 4 + 1], y[v * 4 + 2], y[v * 4 + 3]);
    }

    // per-wave shuffle reduction of sum and sumsq per column, then 1 atomic/wave
#pragma unroll
    for (int c = 0; c < NF; ++c) {
        float s = valid ? y[c] : 0.0f;
        float sq = s * s;
        for (int off = 32; off > 0; off >>= 1) {
            s  += __shfl_down(s, off, 64);
            sq += __shfl_down(sq, off, 64);
        }
        if ((threadIdx.x & 63) == 0) {
            unsafeAtomicAdd(&stats[c], s);
            unsafeAtomicAdd(&stats[NF + c], sq);
        }
    }
}

// ---------------- batchnorm + bias + relu ----------------
__global__ __launch_bounds__(256)
void finalize_kernel(const float* __restrict__ h1, const float* __restrict__ stats,
                     const float* __restrict__ gamma, const float* __restrict__ beta,
                     const float* __restrict__ bias, float* __restrict__ out) {
    const int i = blockIdx.x * 256 + threadIdx.x;
    if (i >= NN * NF) return;
    const int c = i & (NF - 1);
    const float invN = 1.0f / (float)NN;
    const float mean = stats[c] * invN;
    const float var  = stats[NF + c] * invN - mean * mean;
    const float scale = rsqrtf(var + BN_EPS) * gamma[c];
    const float shift = beta[c] + bias[c] - mean * scale;
    const float v = fmaf(h1[i], scale, shift);
    out[i] = fmaxf(v, 0.0f);
}

extern "C" void kernel_launch(void* const* d_in, const int* in_sizes, int n_in,
                              void* d_out, int out_size, void* d_ws, size_t ws_size,
                              hipStream_t stream) {
    const float* A     = (const float*)d_in[0];
    const float* X     = (const float*)d_in[1];
    const float* W     = (const float*)d_in[2];
    const float* gamma = (const float*)d_in[3];
    const float* beta  = (const float*)d_in[4];
    const float* bias  = (const float*)d_in[5];
    float* out = (float*)d_out;

    float* h1    = (float*)d_ws;           // [NN][NF]
    float* stats = h1 + (size_t)NN * NF;   // [2][NF]

    zero_ws<<<1024, 256, 0, stream>>>(h1);
    aggregate_kernel<<<ROWBLK * NSEG, 256, 0, stream>>>(A, X, h1);
    transform_kernel<<<(NN + 255) / 256, 256, 0, stream>>>(h1, W, stats);
    finalize_kernel<<<(NN * NF + 255) / 256, 256, 0, stream>>>(h1, stats, gamma, beta, bias, out);
}